// Round 1
// baseline (298.588 us; speedup 1.0000x reference)
//
#include <hip/hip_runtime.h>
#include <stdint.h>

typedef unsigned long long u64;
typedef unsigned int u32;

#define Nn 32
#define Cc 64
#define Hh 128
#define Ww 128
#define HPAD 130
#define WPAD 130
#define NHW_TOT (Nn*Hh*Ww)

// ---------------------------------------------------------------- shared tables
struct ConvShared {
    u64 wlds[640];                      // weight bits, stride 10 per co (16B-aligned rows)
    int tL[64], tR[64], tT[64], tB[64]; // phantom-pad corrections: col-left/right, row-top/bottom
    int c0[64], c2[64], c6[64], c8[64]; // corner single-tap corrections
    int zz[64];                         // zeros (for non-border lanes' table pointer)
};

__device__ __forceinline__ void init_conv_shared(ConvShared& S,
        const u64* __restrict__ wb, const int* __restrict__ wcon) {
    int tid = threadIdx.x;
    for (int i = tid; i < 576; i += 256) {
        int co = i / 9, tap = i - co * 9;
        S.wlds[co * 10 + tap] = wb[i];
    }
    if (tid < 64) {
        int b = tid * 9;
        int a0 = wcon[b+0], a1 = wcon[b+1], a2 = wcon[b+2];
        int a3 = wcon[b+3], a5 = wcon[b+5];
        int a6 = wcon[b+6], a7 = wcon[b+7], a8 = wcon[b+8];
        S.tT[tid] = a0 + a1 + a2;
        S.tB[tid] = a6 + a7 + a8;
        S.tL[tid] = a0 + a3 + a6;
        S.tR[tid] = a2 + a5 + a8;
        S.c0[tid] = a0; S.c2[tid] = a2; S.c6[tid] = a6; S.c8[tid] = a8;
        S.zz[tid] = 0;
    }
}

// 3x3 binary conv at one (pixel, co): xw = 9 packed input words, wl = 9 packed weight words.
// Each tap: dot64 = 64 - 2*popc(x^w); phantom pad taps corrected by caller.
__device__ __forceinline__ int conv9(const u64* __restrict__ wl, const u64* __restrict__ xw) {
    int p0 = __popcll(xw[0] ^ wl[0]);
    p0 += __popcll(xw[1] ^ wl[1]);
    p0 += __popcll(xw[2] ^ wl[2]);
    int p1 = __popcll(xw[3] ^ wl[3]);
    p1 += __popcll(xw[4] ^ wl[4]);
    p1 += __popcll(xw[5] ^ wl[5]);
    int p2 = __popcll(xw[6] ^ wl[6]);
    p2 += __popcll(xw[7] ^ wl[7]);
    p2 += __popcll(xw[8] ^ wl[8]);
    return 576 - 2 * (p0 + p1 + p2);
}

// ---------------------------------------------------------------- pack sign(x) -> u64/pixel
__global__ __launch_bounds__(256) void pack_x_kernel(const float* __restrict__ x,
                                                     u64* __restrict__ xpad) {
    int tid = threadIdx.x;
    int wp = tid & 63;              // float2 pair index: w = 2*wp
    int r = tid >> 6;               // 0..3
    int row = blockIdx.x * 4 + r;   // 0..4095  (n*H + h)
    int n = row >> 7, h = row & 127;
    const float2* xp = (const float2*)(x + ((size_t)(n * Cc) * Hh + h) * Ww) + wp;
    u32 lo0 = 0, hi0 = 0, lo1 = 0, hi1 = 0;
    #pragma unroll
    for (int c = 0; c < 32; ++c) {
        float2 v = xp[c * (Hh * Ww / 2)];
        lo0 |= (__float_as_uint(v.x) >> 31) << c;
        lo1 |= (__float_as_uint(v.y) >> 31) << c;
    }
    #pragma unroll
    for (int c = 32; c < 64; ++c) {
        float2 v = xp[c * (Hh * Ww / 2)];
        hi0 |= (__float_as_uint(v.x) >> 31) << (c - 32);
        hi1 |= (__float_as_uint(v.y) >> 31) << (c - 32);
    }
    u64* dst = xpad + ((size_t)n * HPAD + h + 1) * WPAD + 2 * wp + 1;
    dst[0] = ((u64)hi0 << 32) | lo0;
    dst[1] = ((u64)hi1 << 32) | lo1;
}

// ---------------------------------------------------------------- pack sign(w) + pad corrections
__global__ __launch_bounds__(576) void pack_w_kernel(
        const float* __restrict__ w1, const float* __restrict__ w2,
        u64* __restrict__ w1b, u64* __restrict__ w2b,
        int* __restrict__ wcon1, int* __restrict__ wcon2) {
    int t = threadIdx.x;                 // 0..575 : co = t/9, tap = t%9
    const float* src = blockIdx.x ? w2 : w1;
    u64* db = blockIdx.x ? w2b : w1b;
    int* dc = blockIdx.x ? wcon2 : wcon1;
    int co = t / 9, tap = t - co * 9;
    const float* p = src + (size_t)co * 576 + tap;   // [co][ci][kh][kw], ci stride 9
    u32 lo = 0, hi = 0;
    #pragma unroll
    for (int ci = 0; ci < 32; ++ci)
        lo |= (__float_as_uint(p[ci * 9]) >> 31) << ci;
    #pragma unroll
    for (int ci = 32; ci < 64; ++ci)
        hi |= (__float_as_uint(p[ci * 9]) >> 31) << (ci - 32);
    u64 word = ((u64)hi << 32) | lo;
    db[t] = word;
    dc[t] = 64 - 2 * __popcll(word);     // phantom contribution of a zero-pad tap
}

// ---------------------------------------------------------------- conv + exact BN stats
__global__ __launch_bounds__(256) void conv_stats_kernel(
        const u64* __restrict__ inpad, const u64* __restrict__ wb,
        const int* __restrict__ wcon,
        u64* __restrict__ gsum, u64* __restrict__ gsq) {
    __shared__ ConvShared S;
    __shared__ short vlds[256 * 66];    // [thread][co], stride 66 shorts: conflict-free both phases
    int tid = threadIdx.x;
    init_conv_shared(S, wb, wcon);
    __syncthreads();
    int w = tid & 127, r = tid >> 7;
    bool fL = (w == 0), fR = (w == 127);
    const int* pcol = fL ? S.tL : (fR ? S.tR : S.zz);
    const int* pT = fL ? S.c0 : (fR ? S.c2 : S.zz);
    const int* pB = fL ? S.c6 : (fR ? S.c8 : S.zz);
    int co2 = tid & 63, grp = tid >> 6;
    int sAcc = 0, qAcc = 0;
    for (int it = 0; it < 4; ++it) {
        int row = blockIdx.x * 8 + it * 2 + r;
        int n = row >> 7, h = row & 127;
        const u64* base = inpad + ((size_t)n * HPAD + h) * WPAD + w;
        u64 xw[9];
        xw[0] = base[0];            xw[1] = base[1];            xw[2] = base[2];
        xw[3] = base[WPAD];         xw[4] = base[WPAD + 1];     xw[5] = base[WPAD + 2];
        xw[6] = base[2 * WPAD];     xw[7] = base[2 * WPAD + 1]; xw[8] = base[2 * WPAD + 2];
        bool fT = (h == 0), fB = (h == 127);
        short* vrow = &vlds[tid * 66];
        if (!fT && !fB) {           // wave-uniform fast path (126/128 rows)
            #pragma unroll 8
            for (int co = 0; co < 64; ++co) {
                int v = conv9(&S.wlds[co * 10], xw) - pcol[co];
                vrow[co] = (short)v;
            }
        } else {
            #pragma unroll 8
            for (int co = 0; co < 64; ++co) {
                int v = conv9(&S.wlds[co * 10], xw) - pcol[co];
                if (fT) v -= S.tT[co] - pT[co];
                if (fB) v -= S.tB[co] - pB[co];
                vrow[co] = (short)v;
            }
        }
        __syncthreads();
        // phase 2: transpose-reduce. thread (co2,grp) sums its wave-group's 64 pixels.
        const short* col = &vlds[grp * 64 * 66 + co2];
        #pragma unroll 16
        for (int i = 0; i < 64; ++i) {
            int v = col[i * 66];
            sAcc += v;
            qAcc += v * v;
        }
        __syncthreads();
    }
    int* iscr = (int*)vlds;
    iscr[tid] = sAcc;
    iscr[256 + tid] = qAcc;
    __syncthreads();
    if (tid < 64) {
        int Sv = iscr[tid] + iscr[tid + 64] + iscr[tid + 128] + iscr[tid + 192];
        int Qv = iscr[256 + tid] + iscr[256 + tid + 64] + iscr[256 + tid + 128] + iscr[256 + tid + 192];
        atomicAdd(&gsum[tid], (u64)(long long)Sv);
        atomicAdd(&gsq[tid], (u64)(long long)Qv);
    }
}

// ---------------------------------------------------------------- BN finalize: per-channel affine
__global__ __launch_bounds__(64) void bn_finalize_kernel(
        const u64* __restrict__ sum, const u64* __restrict__ sq,
        const float* __restrict__ g, const float* __restrict__ bet,
        float2* __restrict__ ab) {
    int c = threadIdx.x;
    long long Sv = (long long)sum[c];
    long long Qv = (long long)sq[c];
    double mean = (double)Sv / (double)NHW_TOT;
    double var = (double)Qv / (double)NHW_TOT - mean * mean;
    double invstd = 1.0 / sqrt(var + 1e-5);
    double a = (double)g[c] * invstd;
    double b = (double)bet[c] - a * mean;
    ab[c] = make_float2((float)a, (float)b);
}

// ---------------------------------------------------------------- conv1 recompute -> sign(bn1) bits
template<bool TB>
__device__ __forceinline__ u64 signpack_body(const ConvShared& S, const float2* __restrict__ ablds,
        const u64* xw, const int* pcol, const int* pT, const int* pB, bool fT, bool fB) {
    u32 lo = 0, hi = 0;
    #pragma unroll 8
    for (int co = 0; co < 32; ++co) {
        int v = conv9(&S.wlds[co * 10], xw) - pcol[co];
        if (TB) {
            if (fT) v -= S.tT[co] - pT[co];
            if (fB) v -= S.tB[co] - pB[co];
        }
        float2 c = ablds[co];
        float s = fmaf((float)v, c.x, c.y);
        lo |= (__float_as_uint(s) >> 31) << co;
    }
    #pragma unroll 8
    for (int co = 32; co < 64; ++co) {
        int v = conv9(&S.wlds[co * 10], xw) - pcol[co];
        if (TB) {
            if (fT) v -= S.tT[co] - pT[co];
            if (fB) v -= S.tB[co] - pB[co];
        }
        float2 c = ablds[co];
        float s = fmaf((float)v, c.x, c.y);
        hi |= (__float_as_uint(s) >> 31) << (co - 32);
    }
    return ((u64)hi << 32) | lo;
}

__global__ __launch_bounds__(256) void signpack_kernel(
        const u64* __restrict__ inpad, const u64* __restrict__ wb,
        const int* __restrict__ wcon, const float2* __restrict__ ab,
        u64* __restrict__ outpad) {
    __shared__ ConvShared S;
    __shared__ float2 ablds[64];
    int tid = threadIdx.x;
    init_conv_shared(S, wb, wcon);
    if (tid < 64) ablds[tid] = ab[tid];
    __syncthreads();
    int w = tid & 127, r = tid >> 7;
    int row = blockIdx.x * 2 + r;
    int n = row >> 7, h = row & 127;
    bool fL = (w == 0), fR = (w == 127);
    bool fT = (h == 0), fB = (h == 127);
    const int* pcol = fL ? S.tL : (fR ? S.tR : S.zz);
    const int* pT = fL ? S.c0 : (fR ? S.c2 : S.zz);
    const int* pB = fL ? S.c6 : (fR ? S.c8 : S.zz);
    const u64* base = inpad + ((size_t)n * HPAD + h) * WPAD + w;
    u64 xw[9];
    xw[0] = base[0];            xw[1] = base[1];            xw[2] = base[2];
    xw[3] = base[WPAD];         xw[4] = base[WPAD + 1];     xw[5] = base[WPAD + 2];
    xw[6] = base[2 * WPAD];     xw[7] = base[2 * WPAD + 1]; xw[8] = base[2 * WPAD + 2];
    u64 word;
    if (!fT && !fB)
        word = signpack_body<false>(S, ablds, xw, pcol, pT, pB, fT, fB);
    else
        word = signpack_body<true>(S, ablds, xw, pcol, pT, pB, fT, fB);
    outpad[((size_t)n * HPAD + h + 1) * WPAD + (w + 1)] = word;
}

// ---------------------------------------------------------------- conv2 recompute + bn2 + residual + hardtanh
template<bool TB>
__device__ __forceinline__ void final_body(const ConvShared& S, const float2* __restrict__ ablds,
        const u64* xw, const int* pcol, const int* pT, const int* pB, bool fT, bool fB,
        const float* __restrict__ xp, float* __restrict__ op) {
    #pragma unroll 8
    for (int co = 0; co < 64; ++co) {
        int v = conv9(&S.wlds[co * 10], xw) - pcol[co];
        if (TB) {
            if (fT) v -= S.tT[co] - pT[co];
            if (fB) v -= S.tB[co] - pB[co];
        }
        float2 c = ablds[co];
        float y = fmaf((float)v, c.x, c.y) + xp[(size_t)co * (Hh * Ww)];
        y = fminf(1.0f, fmaxf(-1.0f, y));
        op[(size_t)co * (Hh * Ww)] = y;
    }
}

__global__ __launch_bounds__(256) void final_kernel(
        const u64* __restrict__ inpad, const u64* __restrict__ wb,
        const int* __restrict__ wcon, const float2* __restrict__ ab,
        const float* __restrict__ x, float* __restrict__ out) {
    __shared__ ConvShared S;
    __shared__ float2 ablds[64];
    int tid = threadIdx.x;
    init_conv_shared(S, wb, wcon);
    if (tid < 64) ablds[tid] = ab[tid];
    __syncthreads();
    int w = tid & 127, r = tid >> 7;
    int row = blockIdx.x * 2 + r;
    int n = row >> 7, h = row & 127;
    bool fL = (w == 0), fR = (w == 127);
    bool fT = (h == 0), fB = (h == 127);
    const int* pcol = fL ? S.tL : (fR ? S.tR : S.zz);
    const int* pT = fL ? S.c0 : (fR ? S.c2 : S.zz);
    const int* pB = fL ? S.c6 : (fR ? S.c8 : S.zz);
    const u64* base = inpad + ((size_t)n * HPAD + h) * WPAD + w;
    u64 xw[9];
    xw[0] = base[0];            xw[1] = base[1];            xw[2] = base[2];
    xw[3] = base[WPAD];         xw[4] = base[WPAD + 1];     xw[5] = base[WPAD + 2];
    xw[6] = base[2 * WPAD];     xw[7] = base[2 * WPAD + 1]; xw[8] = base[2 * WPAD + 2];
    size_t off = ((size_t)n * Cc * Hh + h) * Ww + w;
    const float* xp = x + off;
    float* op = out + off;
    if (!fT && !fB)
        final_body<false>(S, ablds, xw, pcol, pT, pB, fT, fB, xp, op);
    else
        final_body<true>(S, ablds, xw, pcol, pT, pB, fT, fB, xp, op);
}

// ---------------------------------------------------------------- launch
extern "C" void kernel_launch(void* const* d_in, const int* in_sizes, int n_in,
                              void* d_out, int out_size, void* d_ws, size_t ws_size,
                              hipStream_t stream) {
    const float* x  = (const float*)d_in[0];
    const float* w1 = (const float*)d_in[1];
    const float* g1 = (const float*)d_in[2];
    const float* b1 = (const float*)d_in[3];
    const float* w2 = (const float*)d_in[4];
    const float* g2 = (const float*)d_in[5];
    const float* b2 = (const float*)d_in[6];
    float* out = (float*)d_out;
    char* ws = (char*)d_ws;

    constexpr size_t SZ_PAD   = (size_t)Nn * HPAD * WPAD * sizeof(u64);  // 4,326,400 B
    constexpr size_t OFF_YPAD = SZ_PAD;
    constexpr size_t OFF_W1B  = 2 * SZ_PAD;
    constexpr size_t OFF_W2B  = OFF_W1B + 576 * 8;
    constexpr size_t OFF_WCON1 = OFF_W2B + 576 * 8;
    constexpr size_t OFF_WCON2 = OFF_WCON1 + 576 * 4;
    constexpr size_t OFF_SUM1 = OFF_WCON2 + 576 * 4;
    constexpr size_t OFF_SQ1  = OFF_SUM1 + 64 * 8;
    constexpr size_t OFF_SUM2 = OFF_SQ1 + 64 * 8;
    constexpr size_t OFF_SQ2  = OFF_SUM2 + 64 * 8;
    constexpr size_t OFF_AB1  = OFF_SQ2 + 64 * 8;
    constexpr size_t OFF_AB2  = OFF_AB1 + 64 * 8;
    constexpr size_t WS_NEEDED = OFF_AB2 + 64 * 8;   // ~8.67 MB

    if (ws_size < WS_NEEDED) return;

    u64* xpad = (u64*)(ws);
    u64* ypad = (u64*)(ws + OFF_YPAD);
    u64* w1b  = (u64*)(ws + OFF_W1B);
    u64* w2b  = (u64*)(ws + OFF_W2B);
    int* wcon1 = (int*)(ws + OFF_WCON1);
    int* wcon2 = (int*)(ws + OFF_WCON2);
    u64* sum1 = (u64*)(ws + OFF_SUM1);
    u64* sq1  = (u64*)(ws + OFF_SQ1);
    u64* sum2 = (u64*)(ws + OFF_SUM2);
    u64* sq2  = (u64*)(ws + OFF_SQ2);
    float2* ab1 = (float2*)(ws + OFF_AB1);
    float2* ab2 = (float2*)(ws + OFF_AB2);

    // zero pad borders of both bit tensors + the integer stat accumulators (every call)
    hipMemsetAsync(ws, 0, 2 * SZ_PAD, stream);
    hipMemsetAsync(ws + OFF_SUM1, 0, 4 * 64 * 8, stream);

    pack_x_kernel<<<1024, 256, 0, stream>>>(x, xpad);
    pack_w_kernel<<<2, 576, 0, stream>>>(w1, w2, w1b, w2b, wcon1, wcon2);
    conv_stats_kernel<<<512, 256, 0, stream>>>(xpad, w1b, wcon1, sum1, sq1);
    bn_finalize_kernel<<<1, 64, 0, stream>>>(sum1, sq1, g1, b1, ab1);
    signpack_kernel<<<2048, 256, 0, stream>>>(xpad, w1b, wcon1, ab1, ypad);
    conv_stats_kernel<<<512, 256, 0, stream>>>(ypad, w2b, wcon2, sum2, sq2);
    bn_finalize_kernel<<<1, 64, 0, stream>>>(sum2, sq2, g2, b2, ab2);
    final_kernel<<<2048, 256, 0, stream>>>(ypad, w2b, wcon2, ab2, x, out);
}

// Round 2
// 245.126 us; speedup vs baseline: 1.2181x; 1.2181x over previous
//
#include <hip/hip_runtime.h>
#include <stdint.h>

typedef unsigned long long u64;
typedef unsigned int u32;

#define Nn 32
#define Cc 64
#define Hh 128
#define Ww 128
#define HPAD 130
#define WPAD 130
#define NHW_TOT (Nn*Hh*Ww)
#define NBIN 8

// ---------------------------------------------------------------- pack sign(x) -> u64/pixel
__global__ __launch_bounds__(256) void pack_x_kernel(const float* __restrict__ x,
                                                     u64* __restrict__ xpad) {
    int tid = threadIdx.x;
    int wp = tid & 63;              // float2 pair index: w = 2*wp
    int r = tid >> 6;               // 0..3
    int row = blockIdx.x * 4 + r;   // 0..4095  (n*H + h)
    int n = row >> 7, h = row & 127;
    const float2* xp = (const float2*)(x + ((size_t)(n * Cc) * Hh + h) * Ww) + wp;
    u32 lo0 = 0, hi0 = 0, lo1 = 0, hi1 = 0;
    #pragma unroll
    for (int c = 0; c < 32; ++c) {
        float2 v = xp[c * (Hh * Ww / 2)];
        lo0 |= (__float_as_uint(v.x) >> 31) << c;
        lo1 |= (__float_as_uint(v.y) >> 31) << c;
    }
    #pragma unroll
    for (int c = 32; c < 64; ++c) {
        float2 v = xp[c * (Hh * Ww / 2)];
        hi0 |= (__float_as_uint(v.x) >> 31) << (c - 32);
        hi1 |= (__float_as_uint(v.y) >> 31) << (c - 32);
    }
    u64* dst = xpad + ((size_t)n * HPAD + h + 1) * WPAD + 2 * wp + 1;
    dst[0] = ((u64)hi0 << 32) | lo0;
    dst[1] = ((u64)hi1 << 32) | lo1;
}

// ---------------------------------------------------------------- pack sign(w) bits
__global__ __launch_bounds__(576) void pack_w_kernel(
        const float* __restrict__ w1, const float* __restrict__ w2,
        u64* __restrict__ w1b, u64* __restrict__ w2b) {
    int t = threadIdx.x;                 // 0..575 : co = t/9, tap = t%9
    const float* src = blockIdx.x ? w2 : w1;
    u64* db = blockIdx.x ? w2b : w1b;
    int co = t / 9, tap = t - co * 9;
    const float* p = src + (size_t)co * 576 + tap;   // [co][ci][kh][kw], ci stride 9
    u32 lo = 0, hi = 0;
    #pragma unroll
    for (int ci = 0; ci < 32; ++ci)
        lo |= (__float_as_uint(p[ci * 9]) >> 31) << ci;
    #pragma unroll
    for (int ci = 32; ci < 64; ++ci)
        hi |= (__float_as_uint(p[ci * 9]) >> 31) << (ci - 32);
    db[t] = ((u64)hi << 32) | lo;
}

// ---------------------------------------------------------------- model-B conv core
// Wave processes one row; lane = output channel. Window rows staged in LDS
// (uniform broadcast reads); weights in per-lane registers.
__device__ __forceinline__ void conv4(const u64* __restrict__ L0, const u64* __restrict__ L1,
                                      const u64* __restrict__ L2, int w,
                                      const u64 W[9], int corrMid, int v[4]) {
    u64 a[6], b[6], c[6];
    #pragma unroll
    for (int j = 0; j < 6; ++j) { a[j] = L0[w + j]; b[j] = L1[w + j]; c[j] = L2[w + j]; }
    #pragma unroll
    for (int px = 0; px < 4; ++px) {
        int p0 = __popcll(a[px] ^ W[0]) + __popcll(a[px + 1] ^ W[1]) + __popcll(a[px + 2] ^ W[2]);
        int p1 = __popcll(b[px] ^ W[3]) + __popcll(b[px + 1] ^ W[4]) + __popcll(b[px + 2] ^ W[5]);
        int p2 = __popcll(c[px] ^ W[6]) + __popcll(c[px + 1] ^ W[7]) + __popcll(c[px + 2] ^ W[8]);
        v[px] = 576 - 2 * (p0 + p1 + p2) - corrMid;
    }
}

// Common per-wave preamble values
struct LaneCtx {
    u64 W[9];
    int corrMid, corrW0, corrW127;
    int n, h;
};

__device__ __forceinline__ void lane_setup(LaneCtx& C, const u64* __restrict__ wb,
                                           int lane, int blk, int wv) {
    C.n = blk >> 5;
    int hb = (blk & 31) << 2;
    C.h = hb + wv;
    #pragma unroll
    for (int t = 0; t < 9; ++t) C.W[t] = wb[lane * 9 + t];
    int wc[9];
    #pragma unroll
    for (int t = 0; t < 9; ++t) wc[t] = 64 - 2 * __popcll(C.W[t]);
    int tT = wc[0] + wc[1] + wc[2], tB = wc[6] + wc[7] + wc[8];
    int tL = wc[0] + wc[3] + wc[6], tR = wc[2] + wc[5] + wc[8];
    bool fT = (C.h == 0), fB = (C.h == 127);
    C.corrMid  = (fT ? tT : 0) + (fB ? tB : 0);
    C.corrW0   = tL - (fT ? wc[0] : 0) - (fB ? wc[6] : 0);
    C.corrW127 = tR - (fT ? wc[2] : 0) - (fB ? wc[8] : 0);
}

// ---------------------------------------------------------------- conv + exact BN stats
__global__ __launch_bounds__(256) void conv_statsB(const u64* __restrict__ inpad,
        const u64* __restrict__ wb, u64* __restrict__ gsum, u64* __restrict__ gsq) {
    __shared__ u64 win[6 * 130];
    int tid = threadIdx.x;
    int lane = tid & 63;
    int wv = __builtin_amdgcn_readfirstlane(tid >> 6);
    int blk = blockIdx.x;
    int n = blk >> 5, hb = (blk & 31) << 2;
    const u64* src = inpad + ((size_t)n * HPAD + hb) * WPAD;
    for (int i = tid; i < 780; i += 256) win[i] = src[i];
    LaneCtx C;
    lane_setup(C, wb, lane, blk, wv);
    __syncthreads();
    const u64* L0 = &win[wv * 130];
    const u64* L1 = L0 + 130;
    const u64* L2 = L0 + 260;
    int s = 0, q = 0;
    for (int w = 0; w < 128; w += 4) {
        int v[4];
        conv4(L0, L1, L2, w, C.W, C.corrMid, v);
        if (w == 0)   v[0] -= C.corrW0;
        if (w == 124) v[3] -= C.corrW127;
        #pragma unroll
        for (int px = 0; px < 4; ++px) { s += v[px]; q += __mul24(v[px], v[px]); }
    }
    __syncthreads();
    int* r32 = (int*)win;
    r32[wv * 64 + lane] = s;
    r32[256 + wv * 64 + lane] = q;
    __syncthreads();
    if (wv == 0) {
        int S = r32[lane] + r32[64 + lane] + r32[128 + lane] + r32[192 + lane];
        int Q = r32[256 + lane] + r32[320 + lane] + r32[384 + lane] + r32[448 + lane];
        int bin = blk & (NBIN - 1);
        atomicAdd(&gsum[bin * 64 + lane], (u64)(long long)S);
        atomicAdd(&gsq[bin * 64 + lane], (u64)(long long)Q);
    }
}

// ---------------------------------------------------------------- BN finalize (8 bins)
__global__ __launch_bounds__(64) void bn_finalize_kernel(
        const u64* __restrict__ sum, const u64* __restrict__ sq,
        const float* __restrict__ g, const float* __restrict__ bet,
        float2* __restrict__ ab) {
    int c = threadIdx.x;
    long long Sv = 0, Qv = 0;
    #pragma unroll
    for (int b = 0; b < NBIN; ++b) {
        Sv += (long long)sum[b * 64 + c];
        Qv += (long long)sq[b * 64 + c];
    }
    double mean = (double)Sv / (double)NHW_TOT;
    double var = (double)Qv / (double)NHW_TOT - mean * mean;
    double invstd = 1.0 / sqrt(var + 1e-5);
    double a = (double)g[c] * invstd;
    double b_ = (double)bet[c] - a * mean;
    ab[c] = make_float2((float)a, (float)b_);
}

// ---------------------------------------------------------------- conv1 + sign(bn1) -> ballot pack
__global__ __launch_bounds__(256) void signpackB(const u64* __restrict__ inpad,
        const u64* __restrict__ wb, const float2* __restrict__ ab,
        u64* __restrict__ outpad) {
    __shared__ u64 win[6 * 130];
    int tid = threadIdx.x;
    int lane = tid & 63;
    int wv = __builtin_amdgcn_readfirstlane(tid >> 6);
    int blk = blockIdx.x;
    int n = blk >> 5, hb = (blk & 31) << 2;
    const u64* src = inpad + ((size_t)n * HPAD + hb) * WPAD;
    for (int i = tid; i < 780; i += 256) win[i] = src[i];
    LaneCtx C;
    lane_setup(C, wb, lane, blk, wv);
    float2 cab = ab[lane];
    float aa = cab.x, bb = cab.y;
    __syncthreads();
    const u64* L0 = &win[wv * 130];
    const u64* L1 = L0 + 130;
    const u64* L2 = L0 + 260;
    u64* drow = outpad + ((size_t)C.n * HPAD + C.h + 1) * WPAD + 1;
    for (int w = 0; w < 128; w += 4) {
        int v[4];
        conv4(L0, L1, L2, w, C.W, C.corrMid, v);
        if (w == 0)   v[0] -= C.corrW0;
        if (w == 124) v[3] -= C.corrW127;
        u64 wd[4];
        #pragma unroll
        for (int px = 0; px < 4; ++px) {
            float t = fmaf((float)v[px], aa, bb);
            wd[px] = __ballot(t < 0.0f);
        }
        if (lane == 0) {
            drow[w] = wd[0]; drow[w + 1] = wd[1]; drow[w + 2] = wd[2]; drow[w + 3] = wd[3];
        }
    }
}

// ---------------------------------------------------------------- conv2 + bn2 + residual + hardtanh
__global__ __launch_bounds__(256) void finalB(const u64* __restrict__ inpad,
        const u64* __restrict__ wb, const float2* __restrict__ ab,
        const float* __restrict__ x, float* __restrict__ out) {
    __shared__ u64 win[6 * 130];
    __shared__ float tile[4][64 * 33];
    int tid = threadIdx.x;
    int lane = tid & 63;
    int wv = __builtin_amdgcn_readfirstlane(tid >> 6);
    int blk = blockIdx.x;
    int n = blk >> 5, hb = (blk & 31) << 2;
    const u64* src = inpad + ((size_t)n * HPAD + hb) * WPAD;
    for (int i = tid; i < 780; i += 256) win[i] = src[i];
    LaneCtx C;
    lane_setup(C, wb, lane, blk, wv);
    float2 cab = ab[lane];
    float aa = cab.x, bb = cab.y;
    __syncthreads();
    const u64* L0 = &win[wv * 130];
    const u64* L1 = L0 + 130;
    const u64* L2 = L0 + 260;
    float* T = tile[wv];
    int hl = lane >> 5, pix = lane & 31;
    size_t fbase = (((size_t)C.n * 64 + hl) * Hh + C.h) * Ww + pix;
    for (int w = 0; w < 128; w += 4) {
        int v[4];
        conv4(L0, L1, L2, w, C.W, C.corrMid, v);
        if (w == 0)   v[0] -= C.corrW0;
        if (w == 124) v[3] -= C.corrW127;
        #pragma unroll
        for (int px = 0; px < 4; ++px) {
            float t = fmaf((float)v[px], aa, bb);
            T[lane * 33 + ((w + px) & 31)] = t;
        }
        if ((w & 31) == 28) {           // flush the finished 32-pixel chunk
            int w0 = w & ~31;
            #pragma unroll 8
            for (int st = 0; st < 32; ++st) {
                int co = st * 2 + hl;
                size_t idx = fbase + ((size_t)st << 15) + w0;   // st*2*16384
                float y = T[co * 33 + pix] + x[idx];
                y = fminf(1.0f, fmaxf(-1.0f, y));
                out[idx] = y;
            }
        }
    }
}

// ---------------------------------------------------------------- launch
extern "C" void kernel_launch(void* const* d_in, const int* in_sizes, int n_in,
                              void* d_out, int out_size, void* d_ws, size_t ws_size,
                              hipStream_t stream) {
    const float* x  = (const float*)d_in[0];
    const float* w1 = (const float*)d_in[1];
    const float* g1 = (const float*)d_in[2];
    const float* b1 = (const float*)d_in[3];
    const float* w2 = (const float*)d_in[4];
    const float* g2 = (const float*)d_in[5];
    const float* b2 = (const float*)d_in[6];
    float* out = (float*)d_out;
    char* ws = (char*)d_ws;

    constexpr size_t SZ_PAD   = (size_t)Nn * HPAD * WPAD * sizeof(u64);  // 4,326,400 B
    constexpr size_t OFF_YPAD = SZ_PAD;
    constexpr size_t OFF_W1B  = 2 * SZ_PAD;
    constexpr size_t OFF_W2B  = OFF_W1B + 576 * 8;
    constexpr size_t OFF_STAT = OFF_W2B + 576 * 8;            // 4 arrays of NBIN*64 u64
    constexpr size_t SZ_STAT  = (size_t)NBIN * 64 * 8;
    constexpr size_t OFF_AB1  = OFF_STAT + 4 * SZ_STAT;
    constexpr size_t OFF_AB2  = OFF_AB1 + 64 * 8;
    constexpr size_t WS_NEEDED = OFF_AB2 + 64 * 8;

    if (ws_size < WS_NEEDED) return;

    u64* xpad = (u64*)(ws);
    u64* ypad = (u64*)(ws + OFF_YPAD);
    u64* w1b  = (u64*)(ws + OFF_W1B);
    u64* w2b  = (u64*)(ws + OFF_W2B);
    u64* gsum1 = (u64*)(ws + OFF_STAT);
    u64* gsq1  = (u64*)(ws + OFF_STAT + SZ_STAT);
    u64* gsum2 = (u64*)(ws + OFF_STAT + 2 * SZ_STAT);
    u64* gsq2  = (u64*)(ws + OFF_STAT + 3 * SZ_STAT);
    float2* ab1 = (float2*)(ws + OFF_AB1);
    float2* ab2 = (float2*)(ws + OFF_AB2);

    hipMemsetAsync(ws, 0, 2 * SZ_PAD, stream);                 // zero pad borders
    hipMemsetAsync(ws + OFF_STAT, 0, 4 * SZ_STAT, stream);     // zero stat bins

    pack_x_kernel<<<1024, 256, 0, stream>>>(x, xpad);
    pack_w_kernel<<<2, 576, 0, stream>>>(w1, w2, w1b, w2b);
    conv_statsB<<<1024, 256, 0, stream>>>(xpad, w1b, gsum1, gsq1);
    bn_finalize_kernel<<<1, 64, 0, stream>>>(gsum1, gsq1, g1, b1, ab1);
    signpackB<<<1024, 256, 0, stream>>>(xpad, w1b, ab1, ypad);
    conv_statsB<<<1024, 256, 0, stream>>>(ypad, w2b, gsum2, gsq2);
    bn_finalize_kernel<<<1, 64, 0, stream>>>(gsum2, gsq2, g2, b2, ab2);
    finalB<<<1024, 256, 0, stream>>>(ypad, w2b, ab2, x, out);
}

// Round 3
// 228.069 us; speedup vs baseline: 1.3092x; 1.0748x over previous
//
#include <hip/hip_runtime.h>
#include <stdint.h>

typedef unsigned long long u64;
typedef unsigned int u32;

#define Nn 32
#define Cc 64
#define Hh 128
#define Ww 128
#define HPAD 130
#define WPAD 130
#define NHW_TOT (Nn*Hh*Ww)
#define NBIN 8

// ---------------------------------------------------------------- BN finalize (in-kernel, per-lane c)
__device__ __forceinline__ float2 compute_ab(const u64* __restrict__ sum, const u64* __restrict__ sq,
        const float* __restrict__ g, const float* __restrict__ bet, int c) {
    long long Sv = 0, Qv = 0;
    #pragma unroll
    for (int b = 0; b < NBIN; ++b) {
        Sv += (long long)sum[b * 64 + c];
        Qv += (long long)sq[b * 64 + c];
    }
    double mean = (double)Sv / (double)NHW_TOT;
    double var = (double)Qv / (double)NHW_TOT - mean * mean;
    double invstd = 1.0 / sqrt(var + 1e-5);
    double a = (double)g[c] * invstd;
    double b_ = (double)bet[c] - a * mean;
    return make_float2((float)a, (float)b_);
}

// ---------------------------------------------------------------- pack sign(x) -> u64/pixel (float4)
__global__ __launch_bounds__(256) void pack_x4_kernel(const float* __restrict__ x,
                                                      u64* __restrict__ xpad) {
    int t = blockIdx.x * 256 + threadIdx.x;
    int P = t * 4;                      // pixel index, multiple of 4
    int row = P >> 7, w0 = P & 127;     // row = n*128+h
    int n = row >> 7, h = row & 127;
    const float4* xp4 = (const float4*)(x + ((size_t)n * Cc * Hh + h) * Ww + w0);
    u32 lo0 = 0, lo1 = 0, lo2 = 0, lo3 = 0, hi0 = 0, hi1 = 0, hi2 = 0, hi3 = 0;
    #pragma unroll 8
    for (int c = 0; c < 32; ++c) {
        float4 v = xp4[c * (Hh * Ww / 4)];
        lo0 |= (__float_as_uint(v.x) >> 31) << c;
        lo1 |= (__float_as_uint(v.y) >> 31) << c;
        lo2 |= (__float_as_uint(v.z) >> 31) << c;
        lo3 |= (__float_as_uint(v.w) >> 31) << c;
    }
    #pragma unroll 8
    for (int c = 32; c < 64; ++c) {
        float4 v = xp4[c * (Hh * Ww / 4)];
        hi0 |= (__float_as_uint(v.x) >> 31) << (c - 32);
        hi1 |= (__float_as_uint(v.y) >> 31) << (c - 32);
        hi2 |= (__float_as_uint(v.z) >> 31) << (c - 32);
        hi3 |= (__float_as_uint(v.w) >> 31) << (c - 32);
    }
    u64* dst = xpad + ((size_t)n * HPAD + h + 1) * WPAD + w0 + 1;
    dst[0] = ((u64)hi0 << 32) | lo0;
    dst[1] = ((u64)hi1 << 32) | lo1;
    dst[2] = ((u64)hi2 << 32) | lo2;
    dst[3] = ((u64)hi3 << 32) | lo3;
}

// ---------------------------------------------------------------- pack sign(w) bits
__global__ __launch_bounds__(576) void pack_w_kernel(
        const float* __restrict__ w1, const float* __restrict__ w2,
        u64* __restrict__ w1b, u64* __restrict__ w2b) {
    int t = threadIdx.x;                 // 0..575 : co = t/9, tap = t%9
    const float* src = blockIdx.x ? w2 : w1;
    u64* db = blockIdx.x ? w2b : w1b;
    int co = t / 9, tap = t - co * 9;
    const float* p = src + (size_t)co * 576 + tap;   // [co][ci][kh][kw], ci stride 9
    u32 lo = 0, hi = 0;
    #pragma unroll
    for (int ci = 0; ci < 32; ++ci)
        lo |= (__float_as_uint(p[ci * 9]) >> 31) << ci;
    #pragma unroll
    for (int ci = 32; ci < 64; ++ci)
        hi |= (__float_as_uint(p[ci * 9]) >> 31) << (ci - 32);
    db[t] = ((u64)hi << 32) | lo;
}

// ---------------------------------------------------------------- conv core: lane = co, wave = row
__device__ __forceinline__ void conv4(const u64* __restrict__ L0, const u64* __restrict__ L1,
                                      const u64* __restrict__ L2, int w,
                                      const u64 W[9], int corrMid, int v[4]) {
    u64 a[6], b[6], c[6];
    #pragma unroll
    for (int j = 0; j < 6; ++j) { a[j] = L0[w + j]; b[j] = L1[w + j]; c[j] = L2[w + j]; }
    #pragma unroll
    for (int px = 0; px < 4; ++px) {
        int p0 = __popcll(a[px] ^ W[0]) + __popcll(a[px + 1] ^ W[1]) + __popcll(a[px + 2] ^ W[2]);
        int p1 = __popcll(b[px] ^ W[3]) + __popcll(b[px + 1] ^ W[4]) + __popcll(b[px + 2] ^ W[5]);
        int p2 = __popcll(c[px] ^ W[6]) + __popcll(c[px + 1] ^ W[7]) + __popcll(c[px + 2] ^ W[8]);
        v[px] = 576 - 2 * (p0 + p1 + p2) - corrMid;
    }
}

struct LaneCtx {
    u64 W[9];
    int corrMid, corrW0, corrW127;
    int n, h;
};

__device__ __forceinline__ void lane_setup(LaneCtx& C, const u64* __restrict__ wb,
                                           int lane, int blk, int wv) {
    C.n = blk >> 5;
    int hb = (blk & 31) << 2;
    C.h = hb + wv;
    #pragma unroll
    for (int t = 0; t < 9; ++t) C.W[t] = wb[lane * 9 + t];
    int wc[9];
    #pragma unroll
    for (int t = 0; t < 9; ++t) wc[t] = 64 - 2 * __popcll(C.W[t]);
    int tT = wc[0] + wc[1] + wc[2], tB = wc[6] + wc[7] + wc[8];
    int tL = wc[0] + wc[3] + wc[6], tR = wc[2] + wc[5] + wc[8];
    bool fT = (C.h == 0), fB = (C.h == 127);
    C.corrMid  = (fT ? tT : 0) + (fB ? tB : 0);
    C.corrW0   = tL - (fT ? wc[0] : 0) - (fB ? wc[6] : 0);
    C.corrW127 = tR - (fT ? wc[2] : 0) - (fB ? wc[8] : 0);
}

// ---------------------------------------------------------------- conv + exact BN stats (+ optional v16 spill)
template<bool SPILL>
__global__ __launch_bounds__(256) void conv_statsT(const u64* __restrict__ inpad,
        const u64* __restrict__ wb, u64* __restrict__ gsum, u64* __restrict__ gsq,
        short* __restrict__ v16) {
    __shared__ u64 win[6 * 130];
    int tid = threadIdx.x;
    int lane = tid & 63;
    int wv = __builtin_amdgcn_readfirstlane(tid >> 6);
    int blk = blockIdx.x;
    int n = blk >> 5, hb = (blk & 31) << 2;
    const u64* src = inpad + ((size_t)n * HPAD + hb) * WPAD;
    for (int i = tid; i < 780; i += 256) win[i] = src[i];
    LaneCtx C;
    lane_setup(C, wb, lane, blk, wv);
    __syncthreads();
    const u64* L0 = &win[wv * 130];
    const u64* L1 = L0 + 130;
    const u64* L2 = L0 + 260;
    short* vrow = SPILL ? (v16 + ((size_t)(C.n * Hh + C.h) * Ww) * 64 + lane) : nullptr;
    int s = 0, q = 0;
    for (int w = 0; w < 128; w += 4) {
        int v[4];
        conv4(L0, L1, L2, w, C.W, C.corrMid, v);
        if (w == 0)   v[0] -= C.corrW0;
        if (w == 124) v[3] -= C.corrW127;
        #pragma unroll
        for (int px = 0; px < 4; ++px) {
            s += v[px];
            q += __mul24(v[px], v[px]);
            if (SPILL) vrow[(size_t)(w + px) * 64] = (short)v[px];
        }
    }
    __syncthreads();
    int* r32 = (int*)win;
    r32[wv * 64 + lane] = s;
    r32[256 + wv * 64 + lane] = q;
    __syncthreads();
    if (wv == 0) {
        int S = r32[lane] + r32[64 + lane] + r32[128 + lane] + r32[192 + lane];
        int Q = r32[256 + lane] + r32[320 + lane] + r32[384 + lane] + r32[448 + lane];
        int bin = blk & (NBIN - 1);
        atomicAdd(&gsum[bin * 64 + lane], (u64)(long long)S);
        atomicAdd(&gsq[bin * 64 + lane], (u64)(long long)Q);
    }
}

// ---------------------------------------------------------------- sign(bn1(v16)) -> ballot pack (memory pass)
__global__ __launch_bounds__(256) void signpack_v(const short* __restrict__ v16,
        const u64* __restrict__ sum, const u64* __restrict__ sq,
        const float* __restrict__ g, const float* __restrict__ bet,
        u64* __restrict__ ypad) {
    int tid = threadIdx.x;
    int lane = tid & 63;
    int wv = tid >> 6;
    int grow = blockIdx.x * 4 + wv;     // global row
    int n = grow >> 7, h = grow & 127;
    float2 ab = compute_ab(sum, sq, g, bet, lane);
    const short* vr = v16 + (size_t)grow * (Ww * 64) + lane;
    u64* drow = ypad + ((size_t)n * HPAD + h + 1) * WPAD + 1;
    for (int base = 0; base < 128; base += 64) {
        u64 myw = 0;
        #pragma unroll 8
        for (int px = 0; px < 64; ++px) {
            float tv = fmaf((float)vr[(size_t)(base + px) * 64], ab.x, ab.y);
            u64 bal = __ballot(tv < 0.0f);
            if (lane == px) myw = bal;
        }
        drow[base + lane] = myw;
    }
}

// ---------------------------------------------------------------- fallback: conv1 recompute signpack (no spill)
__global__ __launch_bounds__(256) void signpack_rc(const u64* __restrict__ inpad,
        const u64* __restrict__ wb, const u64* __restrict__ sum, const u64* __restrict__ sq,
        const float* __restrict__ g, const float* __restrict__ bet,
        u64* __restrict__ outpad) {
    __shared__ u64 win[6 * 130];
    int tid = threadIdx.x;
    int lane = tid & 63;
    int wv = __builtin_amdgcn_readfirstlane(tid >> 6);
    int blk = blockIdx.x;
    int n = blk >> 5, hb = (blk & 31) << 2;
    const u64* src = inpad + ((size_t)n * HPAD + hb) * WPAD;
    for (int i = tid; i < 780; i += 256) win[i] = src[i];
    LaneCtx C;
    lane_setup(C, wb, lane, blk, wv);
    float2 ab = compute_ab(sum, sq, g, bet, lane);
    __syncthreads();
    const u64* L0 = &win[wv * 130];
    const u64* L1 = L0 + 130;
    const u64* L2 = L0 + 260;
    u64* drow = outpad + ((size_t)C.n * HPAD + C.h + 1) * WPAD + 1;
    for (int w = 0; w < 128; w += 4) {
        int v[4];
        conv4(L0, L1, L2, w, C.W, C.corrMid, v);
        if (w == 0)   v[0] -= C.corrW0;
        if (w == 124) v[3] -= C.corrW127;
        u64 wd[4];
        #pragma unroll
        for (int px = 0; px < 4; ++px) {
            float t = fmaf((float)v[px], ab.x, ab.y);
            wd[px] = __ballot(t < 0.0f);
        }
        if (lane == 0) {
            drow[w] = wd[0]; drow[w + 1] = wd[1]; drow[w + 2] = wd[2]; drow[w + 3] = wd[3];
        }
    }
}

// ---------------------------------------------------------------- conv2 + bn2 + residual + hardtanh (float4 I/O)
__global__ __launch_bounds__(256) void final4_kernel(const u64* __restrict__ inpad,
        const u64* __restrict__ wb, const u64* __restrict__ sum, const u64* __restrict__ sq,
        const float* __restrict__ g, const float* __restrict__ bet,
        const float* __restrict__ x, float* __restrict__ out) {
    __shared__ u64 win[6 * 130];
    __shared__ float tile[4][64 * 33];
    int tid = threadIdx.x;
    int lane = tid & 63;
    int wv = __builtin_amdgcn_readfirstlane(tid >> 6);
    int blk = blockIdx.x;
    int n = blk >> 5, hb = (blk & 31) << 2;
    const u64* src = inpad + ((size_t)n * HPAD + hb) * WPAD;
    for (int i = tid; i < 780; i += 256) win[i] = src[i];
    LaneCtx C;
    lane_setup(C, wb, lane, blk, wv);
    float2 ab = compute_ab(sum, sq, g, bet, lane);
    float aa = ab.x, bb = ab.y;
    __syncthreads();
    const u64* L0 = &win[wv * 130];
    const u64* L1 = L0 + 130;
    const u64* L2 = L0 + 260;
    float* T = tile[wv];
    int p4 = lane & 7;                  // pixel quad within 32-px chunk
    int cosub = lane >> 3;              // 8 channels per flush iter
    size_t base_nch = ((size_t)C.n * Cc * Hh + C.h) * Ww;   // [n][0][h][0]
    for (int w = 0; w < 128; w += 4) {
        int v[4];
        conv4(L0, L1, L2, w, C.W, C.corrMid, v);
        if (w == 0)   v[0] -= C.corrW0;
        if (w == 124) v[3] -= C.corrW127;
        #pragma unroll
        for (int px = 0; px < 4; ++px) {
            float t = fmaf((float)v[px], aa, bb);
            T[lane * 33 + ((w + px) & 31)] = t;
        }
        if ((w & 31) == 28) {           // flush the finished 32-pixel chunk
            int w0 = w & ~31;
            #pragma unroll 8
            for (int st = 0; st < 8; ++st) {
                int co = st * 8 + cosub;
                size_t idx = base_nch + (size_t)co * (Hh * Ww) + w0 + p4 * 4;
                float4 xv = *(const float4*)(x + idx);
                float y0 = T[co * 33 + p4 * 4 + 0] + xv.x;
                float y1 = T[co * 33 + p4 * 4 + 1] + xv.y;
                float y2 = T[co * 33 + p4 * 4 + 2] + xv.z;
                float y3 = T[co * 33 + p4 * 4 + 3] + xv.w;
                float4 yv;
                yv.x = fminf(1.0f, fmaxf(-1.0f, y0));
                yv.y = fminf(1.0f, fmaxf(-1.0f, y1));
                yv.z = fminf(1.0f, fmaxf(-1.0f, y2));
                yv.w = fminf(1.0f, fmaxf(-1.0f, y3));
                *(float4*)(out + idx) = yv;
            }
        }
    }
}

// ---------------------------------------------------------------- launch
extern "C" void kernel_launch(void* const* d_in, const int* in_sizes, int n_in,
                              void* d_out, int out_size, void* d_ws, size_t ws_size,
                              hipStream_t stream) {
    const float* x  = (const float*)d_in[0];
    const float* w1 = (const float*)d_in[1];
    const float* g1 = (const float*)d_in[2];
    const float* b1 = (const float*)d_in[3];
    const float* w2 = (const float*)d_in[4];
    const float* g2 = (const float*)d_in[5];
    const float* b2 = (const float*)d_in[6];
    float* out = (float*)d_out;
    char* ws = (char*)d_ws;

    constexpr size_t SZ_PAD   = (size_t)Nn * HPAD * WPAD * sizeof(u64);  // 4,326,400 B
    constexpr size_t OFF_YPAD = SZ_PAD;
    constexpr size_t OFF_STAT = 2 * SZ_PAD;                   // 4 arrays of NBIN*64 u64
    constexpr size_t SZ_STAT  = (size_t)NBIN * 64 * 8;        // 4096 B
    constexpr size_t OFF_W1B  = OFF_STAT + 4 * SZ_STAT;
    constexpr size_t OFF_W2B  = OFF_W1B + 576 * 8;
    constexpr size_t OFF_V16  = OFF_W2B + 576 * 8;            // 8,678,400 (256B aligned)
    constexpr size_t SZ_V16   = (size_t)Nn * Hh * Ww * 64 * 2; // 64 MiB
    constexpr size_t WS_SMALL = OFF_V16;
    constexpr size_t WS_FULL  = OFF_V16 + SZ_V16;

    if (ws_size < WS_SMALL) return;
    bool spill = (ws_size >= WS_FULL);

    u64* xpad = (u64*)(ws);
    u64* ypad = (u64*)(ws + OFF_YPAD);
    u64* gsum1 = (u64*)(ws + OFF_STAT);
    u64* gsq1  = (u64*)(ws + OFF_STAT + SZ_STAT);
    u64* gsum2 = (u64*)(ws + OFF_STAT + 2 * SZ_STAT);
    u64* gsq2  = (u64*)(ws + OFF_STAT + 3 * SZ_STAT);
    u64* w1b  = (u64*)(ws + OFF_W1B);
    u64* w2b  = (u64*)(ws + OFF_W2B);
    short* v16 = (short*)(ws + OFF_V16);

    // one memset: both pad borders + all stat bins (contiguous)
    hipMemsetAsync(ws, 0, 2 * SZ_PAD + 4 * SZ_STAT, stream);

    pack_x4_kernel<<<512, 256, 0, stream>>>(x, xpad);
    pack_w_kernel<<<2, 576, 0, stream>>>(w1, w2, w1b, w2b);
    if (spill) {
        conv_statsT<true><<<1024, 256, 0, stream>>>(xpad, w1b, gsum1, gsq1, v16);
        signpack_v<<<1024, 256, 0, stream>>>(v16, gsum1, gsq1, g1, b1, ypad);
    } else {
        conv_statsT<false><<<1024, 256, 0, stream>>>(xpad, w1b, gsum1, gsq1, nullptr);
        signpack_rc<<<1024, 256, 0, stream>>>(xpad, w1b, gsum1, gsq1, g1, b1, ypad);
    }
    conv_statsT<false><<<1024, 256, 0, stream>>>(ypad, w2b, gsum2, gsq2, nullptr);
    final4_kernel<<<1024, 256, 0, stream>>>(ypad, w2b, gsum2, gsq2, g2, b2, x, out);
}

// Round 4
// 221.748 us; speedup vs baseline: 1.3465x; 1.0285x over previous
//
#include <hip/hip_runtime.h>
#include <stdint.h>

typedef unsigned long long u64;
typedef unsigned int u32;

#define Nn 32
#define Cc 64
#define Hh 128
#define Ww 128
#define HPAD 130
#define WPAD 130
#define NHW_TOT (Nn*Hh*Ww)
#define NBIN 16

// ---------------------------------------------------------------- BN finalize (in-kernel, per-lane c)
__device__ __forceinline__ float2 compute_ab(const u64* __restrict__ sum, const u64* __restrict__ sq,
        const float* __restrict__ g, const float* __restrict__ bet, int c) {
    long long Sv = 0, Qv = 0;
    #pragma unroll
    for (int b = 0; b < NBIN; ++b) {
        Sv += (long long)sum[b * 64 + c];
        Qv += (long long)sq[b * 64 + c];
    }
    double mean = (double)Sv / (double)NHW_TOT;
    double var = (double)Qv / (double)NHW_TOT - mean * mean;
    double invstd = 1.0 / sqrt(var + 1e-5);
    double a = (double)g[c] * invstd;
    double b_ = (double)bet[c] - a * mean;
    return make_float2((float)a, (float)b_);
}

// ---------------------------------------------------------------- pack sign(x) -> u64/pixel (float4)
__global__ __launch_bounds__(256) void pack_x4_kernel(const float* __restrict__ x,
                                                      u64* __restrict__ xpad) {
    int t = blockIdx.x * 256 + threadIdx.x;
    int P = t * 4;                      // pixel index, multiple of 4
    int row = P >> 7, w0 = P & 127;     // row = n*128+h
    int n = row >> 7, h = row & 127;
    const float4* xp4 = (const float4*)(x + ((size_t)n * Cc * Hh + h) * Ww + w0);
    u32 lo0 = 0, lo1 = 0, lo2 = 0, lo3 = 0, hi0 = 0, hi1 = 0, hi2 = 0, hi3 = 0;
    #pragma unroll 8
    for (int c = 0; c < 32; ++c) {
        float4 v = xp4[c * (Hh * Ww / 4)];
        lo0 |= (__float_as_uint(v.x) >> 31) << c;
        lo1 |= (__float_as_uint(v.y) >> 31) << c;
        lo2 |= (__float_as_uint(v.z) >> 31) << c;
        lo3 |= (__float_as_uint(v.w) >> 31) << c;
    }
    #pragma unroll 8
    for (int c = 32; c < 64; ++c) {
        float4 v = xp4[c * (Hh * Ww / 4)];
        hi0 |= (__float_as_uint(v.x) >> 31) << (c - 32);
        hi1 |= (__float_as_uint(v.y) >> 31) << (c - 32);
        hi2 |= (__float_as_uint(v.z) >> 31) << (c - 32);
        hi3 |= (__float_as_uint(v.w) >> 31) << (c - 32);
    }
    u64* dst = xpad + ((size_t)n * HPAD + h + 1) * WPAD + w0 + 1;
    dst[0] = ((u64)hi0 << 32) | lo0;
    dst[1] = ((u64)hi1 << 32) | lo1;
    dst[2] = ((u64)hi2 << 32) | lo2;
    dst[3] = ((u64)hi3 << 32) | lo3;
}

// ---------------------------------------------------------------- pack sign(w) bits
__global__ __launch_bounds__(576) void pack_w_kernel(
        const float* __restrict__ w1, const float* __restrict__ w2,
        u64* __restrict__ w1b, u64* __restrict__ w2b) {
    int t = threadIdx.x;                 // 0..575 : co = t/9, tap = t%9
    const float* src = blockIdx.x ? w2 : w1;
    u64* db = blockIdx.x ? w2b : w1b;
    int co = t / 9, tap = t - co * 9;
    const float* p = src + (size_t)co * 576 + tap;   // [co][ci][kh][kw], ci stride 9
    u32 lo = 0, hi = 0;
    #pragma unroll
    for (int ci = 0; ci < 32; ++ci)
        lo |= (__float_as_uint(p[ci * 9]) >> 31) << ci;
    #pragma unroll
    for (int ci = 32; ci < 64; ++ci)
        hi |= (__float_as_uint(p[ci * 9]) >> 31) << (ci - 32);
    db[t] = ((u64)hi << 32) | lo;
}

// ---------------------------------------------------------------- conv core: lane = co
__device__ __forceinline__ void conv4(const u64* __restrict__ L0, const u64* __restrict__ L1,
                                      const u64* __restrict__ L2, int w,
                                      const u64 W[9], int corrMid, int v[4]) {
    u64 a[6], b[6], c[6];
    #pragma unroll
    for (int j = 0; j < 6; ++j) { a[j] = L0[w + j]; b[j] = L1[w + j]; c[j] = L2[w + j]; }
    #pragma unroll
    for (int px = 0; px < 4; ++px) {
        int p0 = __popcll(a[px] ^ W[0]) + __popcll(a[px + 1] ^ W[1]) + __popcll(a[px + 2] ^ W[2]);
        int p1 = __popcll(b[px] ^ W[3]) + __popcll(b[px + 1] ^ W[4]) + __popcll(b[px + 2] ^ W[5]);
        int p2 = __popcll(c[px] ^ W[6]) + __popcll(c[px + 1] ^ W[7]) + __popcll(c[px + 2] ^ W[8]);
        v[px] = 576 - 2 * (p0 + p1 + p2) - corrMid;
    }
}

struct LaneCtx {
    u64 W[9];
    int corrMid, corrW0, corrW127;
};

__device__ __forceinline__ void lane_setup(LaneCtx& C, const u64* __restrict__ wb,
                                           int lane, int h) {
    #pragma unroll
    for (int t = 0; t < 9; ++t) C.W[t] = wb[lane * 9 + t];
    int wc[9];
    #pragma unroll
    for (int t = 0; t < 9; ++t) wc[t] = 64 - 2 * __popcll(C.W[t]);
    int tT = wc[0] + wc[1] + wc[2], tB = wc[6] + wc[7] + wc[8];
    int tL = wc[0] + wc[3] + wc[6], tR = wc[2] + wc[5] + wc[8];
    bool fT = (h == 0), fB = (h == 127);
    C.corrMid  = (fT ? tT : 0) + (fB ? tB : 0);
    C.corrW0   = tL - (fT ? wc[0] : 0) - (fB ? wc[6] : 0);
    C.corrW127 = tR - (fT ? wc[2] : 0) - (fB ? wc[8] : 0);
}

// ---------------------------------------------------------------- conv + exact BN stats (+ optional v16 spill)
// block = 128 threads = 2 waves; wave = half-row (64 px). blk = n*128 + hp*2 + half
template<bool SPILL>
__global__ __launch_bounds__(128) void conv_statsT(const u64* __restrict__ inpad,
        const u64* __restrict__ wb, u64* __restrict__ gsum, u64* __restrict__ gsq,
        short* __restrict__ v16) {
    __shared__ u64 win[4 * 68];
    __shared__ int r32[256];
    int tid = threadIdx.x;
    int lane = tid & 63;
    int wv = __builtin_amdgcn_readfirstlane(tid >> 6);   // 0/1
    int blk = blockIdx.x;
    int half = blk & 1;
    int hp = (blk >> 1) & 63;
    int n = blk >> 7;
    int h = hp * 2 + wv;
    const u64* src = inpad + ((size_t)n * HPAD + hp * 2) * WPAD + half * 64;
    for (int i = tid; i < 264; i += 128) {
        int r = i / 66, c = i - r * 66;
        win[r * 68 + c] = src[(size_t)r * WPAD + c];
    }
    LaneCtx C;
    lane_setup(C, wb, lane, h);
    __syncthreads();
    const u64* L0 = &win[wv * 68];
    const u64* L1 = L0 + 68;
    const u64* L2 = L0 + 136;
    short* vrow = SPILL ? (v16 + (((size_t)(n * Hh + h) * Ww) + half * 64) * 64 + lane) : nullptr;
    int s = 0, q = 0;
    for (int w = 0; w < 64; w += 4) {
        int v[4];
        conv4(L0, L1, L2, w, C.W, C.corrMid, v);
        if (half == 0 && w == 0)  v[0] -= C.corrW0;
        if (half == 1 && w == 60) v[3] -= C.corrW127;
        #pragma unroll
        for (int px = 0; px < 4; ++px) {
            s += v[px];
            q += __mul24(v[px], v[px]);
            if (SPILL) vrow[(size_t)(w + px) * 64] = (short)v[px];
        }
    }
    __syncthreads();
    r32[wv * 64 + lane] = s;
    r32[128 + wv * 64 + lane] = q;
    __syncthreads();
    if (wv == 0) {
        int S = r32[lane] + r32[64 + lane];
        int Q = r32[128 + lane] + r32[192 + lane];
        int bin = blk & (NBIN - 1);
        atomicAdd(&gsum[bin * 64 + lane], (u64)(long long)S);
        atomicAdd(&gsq[bin * 64 + lane], (u64)(long long)Q);
    }
}

// ---------------------------------------------------------------- sign(bn1(v16)) -> ballot pack (memory pass)
// block = 256 th = 4 waves; wave = half-row. blk covers rows blk*2, blk*2+1
__global__ __launch_bounds__(256) void signpack_v(const short* __restrict__ v16,
        const u64* __restrict__ sum, const u64* __restrict__ sq,
        const float* __restrict__ g, const float* __restrict__ bet,
        u64* __restrict__ ypad) {
    int tid = threadIdx.x;
    int lane = tid & 63;
    int wv = tid >> 6;
    int grow = blockIdx.x * 2 + (wv >> 1);
    int base = (wv & 1) * 64;
    int n = grow >> 7, h = grow & 127;
    float2 ab = compute_ab(sum, sq, g, bet, lane);
    const short* vr = v16 + ((size_t)grow * Ww + base) * 64;
    u64* drow = ypad + ((size_t)n * HPAD + h + 1) * WPAD + 1;
    u64 myw = 0;
    #pragma unroll 8
    for (int px = 0; px < 64; ++px) {
        float tv = fmaf((float)vr[(size_t)px * 64 + lane], ab.x, ab.y);
        u64 bal = __ballot(tv < 0.0f);
        if (lane == px) myw = bal;
    }
    drow[base + lane] = myw;
}

// ---------------------------------------------------------------- fallback: conv1 recompute signpack (no spill)
__global__ __launch_bounds__(256) void signpack_rc(const u64* __restrict__ inpad,
        const u64* __restrict__ wb, const u64* __restrict__ sum, const u64* __restrict__ sq,
        const float* __restrict__ g, const float* __restrict__ bet,
        u64* __restrict__ outpad) {
    __shared__ u64 win[6 * 130];
    int tid = threadIdx.x;
    int lane = tid & 63;
    int wv = __builtin_amdgcn_readfirstlane(tid >> 6);
    int blk = blockIdx.x;
    int n = blk >> 5, hb = (blk & 31) << 2;
    int h = hb + wv;
    const u64* src = inpad + ((size_t)n * HPAD + hb) * WPAD;
    for (int i = tid; i < 780; i += 256) win[i] = src[i];
    LaneCtx C;
    lane_setup(C, wb, lane, h);
    float2 ab = compute_ab(sum, sq, g, bet, lane);
    __syncthreads();
    const u64* L0 = &win[wv * 130];
    const u64* L1 = L0 + 130;
    const u64* L2 = L0 + 260;
    u64* drow = outpad + ((size_t)n * HPAD + h + 1) * WPAD + 1;
    for (int w = 0; w < 128; w += 4) {
        int v[4];
        conv4(L0, L1, L2, w, C.W, C.corrMid, v);
        if (w == 0)   v[0] -= C.corrW0;
        if (w == 124) v[3] -= C.corrW127;
        u64 wd[4];
        #pragma unroll
        for (int px = 0; px < 4; ++px) {
            float t = fmaf((float)v[px], ab.x, ab.y);
            wd[px] = __ballot(t < 0.0f);
        }
        if (lane == 0) {
            drow[w] = wd[0]; drow[w + 1] = wd[1]; drow[w + 2] = wd[2]; drow[w + 3] = wd[3];
        }
    }
}

// ---------------------------------------------------------------- conv2 + bn2 + residual + hardtanh
// block = 128 th = 2 waves; wave = half-row; int16 tile, BN applied at flush
__global__ __launch_bounds__(128) void final5_kernel(const u64* __restrict__ inpad,
        const u64* __restrict__ wb, const u64* __restrict__ sum, const u64* __restrict__ sq,
        const float* __restrict__ g, const float* __restrict__ bet,
        const float* __restrict__ x, float* __restrict__ out) {
    __shared__ u64 win[4 * 68];
    __shared__ short T[2][64 * 36];
    __shared__ float2 absh[64];
    int tid = threadIdx.x;
    int lane = tid & 63;
    int wv = __builtin_amdgcn_readfirstlane(tid >> 6);   // 0/1
    int blk = blockIdx.x;
    int half = blk & 1;
    int hp = (blk >> 1) & 63;
    int n = blk >> 7;
    int h = hp * 2 + wv;
    const u64* src = inpad + ((size_t)n * HPAD + hp * 2) * WPAD + half * 64;
    for (int i = tid; i < 264; i += 128) {
        int r = i / 66, c = i - r * 66;
        win[r * 68 + c] = src[(size_t)r * WPAD + c];
    }
    LaneCtx C;
    lane_setup(C, wb, lane, h);
    if (tid < 64) absh[tid] = compute_ab(sum, sq, g, bet, tid);
    __syncthreads();
    const u64* L0 = &win[wv * 68];
    const u64* L1 = L0 + 68;
    const u64* L2 = L0 + 136;
    short* Tw = T[wv];
    int p4 = lane & 7;                  // float4 quad within 32-px chunk
    int cosub = lane >> 3;              // 8 channels per flush iter
    size_t base_nch = ((size_t)n * Cc * Hh + h) * Ww;
    for (int w = 0; w < 64; w += 4) {
        int v[4];
        conv4(L0, L1, L2, w, C.W, C.corrMid, v);
        if (half == 0 && w == 0)  v[0] -= C.corrW0;
        if (half == 1 && w == 60) v[3] -= C.corrW127;
        short4 sv;
        sv.x = (short)v[0]; sv.y = (short)v[1]; sv.z = (short)v[2]; sv.w = (short)v[3];
        *(short4*)&Tw[lane * 36 + (w & 31)] = sv;
        if ((w & 31) == 28) {           // flush the finished 32-pixel chunk
            int w0g = half * 64 + (w & ~31);
            #pragma unroll 8
            for (int st = 0; st < 8; ++st) {
                int co = st * 8 + cosub;
                short4 tv = *(const short4*)&Tw[co * 36 + p4 * 4];
                float2 cab = absh[co];
                size_t idx = base_nch + (size_t)co * (Hh * Ww) + w0g + p4 * 4;
                float4 xv = *(const float4*)(x + idx);
                float4 yv;
                yv.x = fminf(1.0f, fmaxf(-1.0f, fmaf((float)tv.x, cab.x, cab.y) + xv.x));
                yv.y = fminf(1.0f, fmaxf(-1.0f, fmaf((float)tv.y, cab.x, cab.y) + xv.y));
                yv.z = fminf(1.0f, fmaxf(-1.0f, fmaf((float)tv.z, cab.x, cab.y) + xv.z));
                yv.w = fminf(1.0f, fmaxf(-1.0f, fmaf((float)tv.w, cab.x, cab.y) + xv.w));
                *(float4*)(out + idx) = yv;
            }
        }
    }
}

// ---------------------------------------------------------------- launch
extern "C" void kernel_launch(void* const* d_in, const int* in_sizes, int n_in,
                              void* d_out, int out_size, void* d_ws, size_t ws_size,
                              hipStream_t stream) {
    const float* x  = (const float*)d_in[0];
    const float* w1 = (const float*)d_in[1];
    const float* g1 = (const float*)d_in[2];
    const float* b1 = (const float*)d_in[3];
    const float* w2 = (const float*)d_in[4];
    const float* g2 = (const float*)d_in[5];
    const float* b2 = (const float*)d_in[6];
    float* out = (float*)d_out;
    char* ws = (char*)d_ws;

    constexpr size_t SZ_PAD   = (size_t)Nn * HPAD * WPAD * sizeof(u64);  // 4,326,400 B
    constexpr size_t OFF_YPAD = SZ_PAD;
    constexpr size_t OFF_STAT = 2 * SZ_PAD;                   // 4 arrays of NBIN*64 u64
    constexpr size_t SZ_STAT  = (size_t)NBIN * 64 * 8;        // 8192 B
    constexpr size_t OFF_W1B  = OFF_STAT + 4 * SZ_STAT;
    constexpr size_t OFF_W2B  = OFF_W1B + 576 * 8;
    constexpr size_t OFF_V16  = OFF_W2B + 576 * 8;
    constexpr size_t SZ_V16   = (size_t)Nn * Hh * Ww * 64 * 2; // 64 MiB
    constexpr size_t WS_SMALL = OFF_V16;
    constexpr size_t WS_FULL  = OFF_V16 + SZ_V16;

    if (ws_size < WS_SMALL) return;
    bool spill = (ws_size >= WS_FULL);

    u64* xpad = (u64*)(ws);
    u64* ypad = (u64*)(ws + OFF_YPAD);
    u64* gsum1 = (u64*)(ws + OFF_STAT);
    u64* gsq1  = (u64*)(ws + OFF_STAT + SZ_STAT);
    u64* gsum2 = (u64*)(ws + OFF_STAT + 2 * SZ_STAT);
    u64* gsq2  = (u64*)(ws + OFF_STAT + 3 * SZ_STAT);
    u64* w1b  = (u64*)(ws + OFF_W1B);
    u64* w2b  = (u64*)(ws + OFF_W2B);
    short* v16 = (short*)(ws + OFF_V16);

    // one memset: both pad borders + all stat bins (contiguous)
    hipMemsetAsync(ws, 0, 2 * SZ_PAD + 4 * SZ_STAT, stream);

    pack_x4_kernel<<<512, 256, 0, stream>>>(x, xpad);
    pack_w_kernel<<<2, 576, 0, stream>>>(w1, w2, w1b, w2b);
    if (spill) {
        conv_statsT<true><<<4096, 128, 0, stream>>>(xpad, w1b, gsum1, gsq1, v16);
        signpack_v<<<2048, 256, 0, stream>>>(v16, gsum1, gsq1, g1, b1, ypad);
    } else {
        conv_statsT<false><<<4096, 128, 0, stream>>>(xpad, w1b, gsum1, gsq1, nullptr);
        signpack_rc<<<1024, 256, 0, stream>>>(xpad, w1b, gsum1, gsq1, g1, b1, ypad);
    }
    conv_statsT<false><<<4096, 128, 0, stream>>>(ypad, w2b, gsum2, gsq2, nullptr);
    final5_kernel<<<4096, 128, 0, stream>>>(ypad, w2b, gsum2, gsq2, g2, b2, x, out);
}